// Round 11
// baseline (54.698 us; speedup 1.0000x reference)
//
#include <hip/hip_runtime.h>
#include <hip/hip_bf16.h>

// Problem constants: B=16384, N=20, D=64, R=3, K=64
#define BB   16384
#define NN   20
#define NREL 3

typedef __attribute__((ext_vector_type(8))) short  short8;
typedef __attribute__((ext_vector_type(4))) float  f32x4;

__device__ __forceinline__ float lo16(unsigned int u) {
    union { unsigned int x; float f; } c; c.x = u << 16; return c.f;
}
__device__ __forceinline__ float hi16(unsigned int u) {
    union { unsigned int x; float f; } c; c.x = u & 0xFFFF0000u; return c.f;
}

// f32 -> bf16 (RNE), returned as raw ushort
__device__ __forceinline__ unsigned short f2bu(float f) {
    union { float f; unsigned int u; } x;
    x.f = f;
    unsigned int r = x.u + 0x7FFFu + ((x.u >> 16) & 1u);
    return (unsigned short)(r >> 16);
}

// ---------------------------------------------------------------------------
// K1: McatT[r*128+e][d] = sum_k w_uir[r][d][k] * w_aor[r][e][k]   (bf16 out)
//     cvec[r*128+e]     = sum_k r_vec[r][k]   * w_aor[r][e][k]    (f32 out)
// ---------------------------------------------------------------------------
__global__ __launch_bounds__(256) void k_precompute(
    const float* __restrict__ w_uir,
    const float* __restrict__ w_aor,
    const float* __restrict__ r_vec,
    unsigned short* __restrict__ McatT,   // [384][128] bf16 bits
    float* __restrict__ cvec)             // [384]
{
    int idx = blockIdx.x * 256 + threadIdx.x;
    if (idx < NREL * 128 * 128) {
        int d = idx & 127;
        int e = (idx >> 7) & 127;
        int r = idx >> 14;
        const float4* pu = reinterpret_cast<const float4*>(w_uir + (r * 128 + d) * 64);
        const float4* pa = reinterpret_cast<const float4*>(w_aor + (r * 128 + e) * 64);
        float acc = 0.f;
        #pragma unroll
        for (int k = 0; k < 16; ++k) {
            float4 a = pu[k], b = pa[k];
            acc += a.x * b.x + a.y * b.y + a.z * b.z + a.w * b.w;
        }
        McatT[(r * 128 + e) * 128 + d] = f2bu(acc);
    } else if (idx < NREL * 128 * 128 + NREL * 128) {
        int j = idx - NREL * 128 * 128;
        int r = j >> 7, e = j & 127;
        const float4* pr = reinterpret_cast<const float4*>(r_vec + r * 64);
        const float4* pa = reinterpret_cast<const float4*>(w_aor + (r * 128 + e) * 64);
        float acc = 0.f;
        #pragma unroll
        for (int k = 0; k < 16; ++k) {
            float4 a = pr[k], b = pa[k];
            acc += a.x * b.x + a.y * b.y + a.z * b.z + a.w * b.w;
        }
        cvec[j] = acc;
    }
}

// ---------------------------------------------------------------------------
// K2: v'[b][j] = sum_d ui_in[b][d] * McatT[j][d] + cvec[j]
//     GEMM M=16384 N=384 K=128, bf16 MFMA 16x16x32, 64x64 block tiles.
// ---------------------------------------------------------------------------
__global__ __launch_bounds__(256) void k_gemm(
    const float* __restrict__ u_emb,
    const float* __restrict__ i_emb,
    const unsigned short* __restrict__ McatT,  // [384][128] bf16 bits
    const float* __restrict__ cvec,            // [384]
    unsigned short* __restrict__ vp)           // [16384][384] bf16 bits
{
    __shared__ unsigned short Atile[64][136];  // +8 pad
    const int t = threadIdx.x;
    const int bm = blockIdx.x & 255;   // 256 M tiles
    const int bn = blockIdx.x >> 8;    // 6 N tiles
    const int Mbase = bm * 64;
    const int Nbase = bn * 64;

    #pragma unroll
    for (int it = 0; it < 8; ++it) {
        int idx  = it * 256 + t;       // 0..2047, each covers 4 floats
        int row  = idx >> 5;
        int colg = idx & 31;
        const float* src = (colg < 16)
            ? (u_emb + (Mbase + row) * 64 + colg * 4)
            : (i_emb + (Mbase + row) * 64 + (colg - 16) * 4);
        float4 v = *reinterpret_cast<const float4*>(src);
        ushort4 h;
        h.x = f2bu(v.x); h.y = f2bu(v.y); h.z = f2bu(v.z); h.w = f2bu(v.w);
        *reinterpret_cast<ushort4*>(&Atile[row][colg * 4]) = h;
    }
    __syncthreads();

    const int w    = t >> 6;
    const int lane = t & 63;
    const int lr   = lane & 15;
    const int lk   = (lane >> 4) * 8;

    short8 afrag[4];
    #pragma unroll
    for (int kk = 0; kk < 4; ++kk)
        afrag[kk] = *reinterpret_cast<const short8*>(&Atile[w * 16 + lr][kk * 32 + lk]);

    #pragma unroll
    for (int nt = 0; nt < 4; ++nt) {
        f32x4 acc = {0.f, 0.f, 0.f, 0.f};
        int col = Nbase + nt * 16 + lr;
        #pragma unroll
        for (int kk = 0; kk < 4; ++kk) {
            short8 bfrag = *reinterpret_cast<const short8*>(McatT + col * 128 + kk * 32 + lk);
            acc = __builtin_amdgcn_mfma_f32_16x16x32_bf16(afrag[kk], bfrag, acc, 0, 0, 0);
        }
        float cb = cvec[col];
        #pragma unroll
        for (int reg = 0; reg < 4; ++reg) {
            int grow = Mbase + w * 16 + (lane >> 4) * 4 + reg;
            vp[grow * 384 + col] = f2bu(acc[reg] + cb);
        }
    }
}

// ---------------------------------------------------------------------------
// K3: pred[t] = sum_e ao_in[t][e] * v'[b][s[t]*128 + e],  ao_in = [a|o]
//     Continuous-feed DMA pipeline, verified primitives only:
//       - all global_load_lds are size 16 (HW-verified width)
//       - prologue: stage slices 0,1 then a FULL __syncthreads drain
//         (zero outstanding at loop entry -- no prologue counting)
//       - loop: stage(it+2) -> counted s_waitcnt vmcnt(N) (6/4 steady,
//         3/2 at it=14, 0 at it=15) -> consume(it) -> RAW s_barrier.
//         vmcnt never drains to 0 until the tail; memory queue never empties.
//       - loop body is vmcnt-pure: consume is LDS-only, outputs buffered
//         in LDS and flushed once at the end.
// ---------------------------------------------------------------------------
#define K3_BLOCKS 1024
#define K3_NITER  16
#define K3_BUF    11264              // A 5120 | O 5120 | VP 768 | pad
#define K3_SOFF   (3 * K3_BUF)      // 33792: s values (320 ints)
#define K3_OOFF   (K3_SOFF + 1280)  // 35072: out buffer (320 f32)
#define K3_LDS    (K3_OOFF + 1280)  // 36352 total

__device__ __forceinline__ void k3_stage(
    const float* __restrict__ a_emb, const float* __restrict__ o_emb,
    const unsigned short* __restrict__ vpg,
    char* buf, int bb, int wv, int lane)
{
    const char* asrc = (const char*)a_emb + (size_t)bb * 5120;
    const char* osrc = (const char*)o_emb + (size_t)bb * 5120;
    if (wv == 0) {
        __builtin_amdgcn_global_load_lds((const unsigned int*)(asrc + 0 * 1024 + lane * 16),
                                         (unsigned int*)(buf + 0 * 1024), 16, 0, 0);
        __builtin_amdgcn_global_load_lds((const unsigned int*)(asrc + 1 * 1024 + lane * 16),
                                         (unsigned int*)(buf + 1 * 1024), 16, 0, 0);
        __builtin_amdgcn_global_load_lds((const unsigned int*)(asrc + 2 * 1024 + lane * 16),
                                         (unsigned int*)(buf + 2 * 1024), 16, 0, 0);
    } else if (wv == 1) {
        __builtin_amdgcn_global_load_lds((const unsigned int*)(asrc + 3 * 1024 + lane * 16),
                                         (unsigned int*)(buf + 3 * 1024), 16, 0, 0);
        __builtin_amdgcn_global_load_lds((const unsigned int*)(asrc + 4 * 1024 + lane * 16),
                                         (unsigned int*)(buf + 4 * 1024), 16, 0, 0);
        __builtin_amdgcn_global_load_lds((const unsigned int*)(osrc + 0 * 1024 + lane * 16),
                                         (unsigned int*)(buf + 5120 + 0 * 1024), 16, 0, 0);
    } else if (wv == 2) {
        __builtin_amdgcn_global_load_lds((const unsigned int*)(osrc + 1 * 1024 + lane * 16),
                                         (unsigned int*)(buf + 5120 + 1 * 1024), 16, 0, 0);
        __builtin_amdgcn_global_load_lds((const unsigned int*)(osrc + 2 * 1024 + lane * 16),
                                         (unsigned int*)(buf + 5120 + 2 * 1024), 16, 0, 0);
        __builtin_amdgcn_global_load_lds((const unsigned int*)(osrc + 3 * 1024 + lane * 16),
                                         (unsigned int*)(buf + 5120 + 3 * 1024), 16, 0, 0);
    } else {
        __builtin_amdgcn_global_load_lds((const unsigned int*)(osrc + 4 * 1024 + lane * 16),
                                         (unsigned int*)(buf + 5120 + 4 * 1024), 16, 0, 0);
        const char* vsrc = (const char*)vpg + (size_t)bb * 768;
        if (lane < 48)
            __builtin_amdgcn_global_load_lds((const unsigned int*)(vsrc + lane * 16),
                                             (unsigned int*)(buf + 10240), 16, 0, 0);
    }
}

__device__ __forceinline__ void k3_consume(
    char* lds, const char* buf, int it, int g, int sub)
{
    // pass 0: triples 0..15 of the slice (one per 16-lane group)
    {
        const int ltrip = g;
        const int sv = *(const int*)(lds + K3_SOFF + (it * 20 + ltrip) * 4);
        float4 af = *(const float4*)(buf + ltrip * 256 + sub * 16);
        float4 of = *(const float4*)(buf + 5120 + ltrip * 256 + sub * 16);
        uint2  wa = *(const uint2*)(buf + 10240 + sv * 256 + sub * 8);
        uint2  wo = *(const uint2*)(buf + 10240 + sv * 256 + 128 + sub * 8);
        float r = af.x * lo16(wa.x) + af.y * hi16(wa.x)
                + af.z * lo16(wa.y) + af.w * hi16(wa.y)
                + of.x * lo16(wo.x) + of.y * hi16(wo.x)
                + of.z * lo16(wo.y) + of.w * hi16(wo.y);
        r += __shfl_xor(r, 1, 64);
        r += __shfl_xor(r, 2, 64);
        r += __shfl_xor(r, 4, 64);
        r += __shfl_xor(r, 8, 64);
        if (sub == 0) *(float*)(lds + K3_OOFF + (it * 20 + ltrip) * 4) = r;
    }
    // pass 1: triples 16..19 (wave 0 only: g<4)
    if (g < 4) {
        const int ltrip = 16 + g;
        const int sv = *(const int*)(lds + K3_SOFF + (it * 20 + ltrip) * 4);
        float4 af = *(const float4*)(buf + ltrip * 256 + sub * 16);
        float4 of = *(const float4*)(buf + 5120 + ltrip * 256 + sub * 16);
        uint2  wa = *(const uint2*)(buf + 10240 + sv * 256 + sub * 8);
        uint2  wo = *(const uint2*)(buf + 10240 + sv * 256 + 128 + sub * 8);
        float r = af.x * lo16(wa.x) + af.y * hi16(wa.x)
                + af.z * lo16(wa.y) + af.w * hi16(wa.y)
                + of.x * lo16(wo.x) + of.y * hi16(wo.x)
                + of.z * lo16(wo.y) + of.w * hi16(wo.y);
        r += __shfl_xor(r, 1, 64);
        r += __shfl_xor(r, 2, 64);
        r += __shfl_xor(r, 4, 64);
        r += __shfl_xor(r, 8, 64);
        if (sub == 0) *(float*)(lds + K3_OOFF + (it * 20 + ltrip) * 4) = r;
    }
}

__global__ __launch_bounds__(256) void k_pred(
    const float* __restrict__ a_emb,
    const float* __restrict__ o_emb,
    const int* __restrict__ s,
    const unsigned short* __restrict__ vpg,
    float* __restrict__ out)
{
    __shared__ __align__(16) char lds[K3_LDS];

    const int tid  = threadIdx.x;
    const int bid  = blockIdx.x;
    const int wv   = tid >> 6;
    const int lane = tid & 63;
    const int g    = tid >> 4;
    const int sub  = tid & 15;
    const size_t t0 = (size_t)bid * (K3_NITER * NN);   // 320 triples per block
    const int  b0  = bid * K3_NITER;

    // ---- prologue: s for all 320 triples + slices 0,1; FULL drain after.
    int sv1 = s[t0 + tid];
    int sv2 = (tid < 64) ? s[t0 + 256 + tid] : 0;

    k3_stage(a_emb, o_emb, vpg, lds + 0 * K3_BUF, b0 + 0, wv, lane);
    k3_stage(a_emb, o_emb, vpg, lds + 1 * K3_BUF, b0 + 1, wv, lane);

    *(int*)(lds + K3_SOFF + tid * 4) = sv1;
    if (tid < 64) *(int*)(lds + K3_SOFF + 1024 + tid * 4) = sv2;
    __syncthreads();   // drains vmcnt+lgkmcnt: slices 0,1 + s all landed

    #pragma unroll
    for (int it = 0; it < K3_NITER; ++it) {
        if (it + 2 < K3_NITER)
            k3_stage(a_emb, o_emb, vpg, lds + ((it + 2) % 3) * K3_BUF,
                     b0 + it + 2, wv, lane);
        __builtin_amdgcn_sched_barrier(0);

        // wait for slice `it`; later slices stay in flight (counted, not 0)
        if (it >= 2) {
            if (it < K3_NITER - 2) {
                if (wv == 3) asm volatile("s_waitcnt vmcnt(4)" ::: "memory");
                else         asm volatile("s_waitcnt vmcnt(6)" ::: "memory");
            } else if (it == K3_NITER - 2) {
                if (wv == 3) asm volatile("s_waitcnt vmcnt(2)" ::: "memory");
                else         asm volatile("s_waitcnt vmcnt(3)" ::: "memory");
            } else {
                asm volatile("s_waitcnt vmcnt(0)" ::: "memory");
            }
        }
        __builtin_amdgcn_sched_barrier(0);

        k3_consume(lds, lds + (it % 3) * K3_BUF, it, g, sub);

        __builtin_amdgcn_sched_barrier(0);
        __builtin_amdgcn_s_barrier();   // raw: all waves done with buf(it)
    }

    __syncthreads();   // final drain before flush
    if (tid < 80) {
        float4 v = *(const float4*)(lds + K3_OOFF + tid * 16);
        *(float4*)(out + t0 + tid * 4) = v;
    }
}

// ---------------------------------------------------------------------------
extern "C" void kernel_launch(void* const* d_in, const int* in_sizes, int n_in,
                              void* d_out, int out_size, void* d_ws, size_t ws_size,
                              hipStream_t stream) {
    const float* u_emb = (const float*)d_in[0];
    const float* i_emb = (const float*)d_in[1];
    const float* a_emb = (const float*)d_in[2];
    const float* o_emb = (const float*)d_in[3];
    const int*   s     = (const int*)d_in[4];
    const float* w_uir = (const float*)d_in[5];
    const float* w_aor = (const float*)d_in[6];
    const float* r_vec = (const float*)d_in[7];
    float* out = (float*)d_out;

    char* ws = (char*)d_ws;
    unsigned short* McatT = (unsigned short*)ws;              // 98304 B
    float*          cvec  = (float*)(ws + 98304);             // 1536 B
    unsigned short* vp    = (unsigned short*)(ws + 102400);   // 12.58 MB

    k_precompute<<<194, 256, 0, stream>>>(w_uir, w_aor, r_vec, McatT, cvec);
    k_gemm<<<1536, 256, 0, stream>>>(u_emb, i_emb, McatT, cvec, vp);
    k_pred<<<K3_BLOCKS, 256, 0, stream>>>(a_emb, o_emb, s, vp, out);
}

// Round 12
// 46.405 us; speedup vs baseline: 1.1787x; 1.1787x over previous
//
#include <hip/hip_runtime.h>
#include <hip/hip_bf16.h>

// Problem constants: B=16384, N=20, D=64, R=3, K=64
#define BB   16384
#define NN   20
#define NREL 3

typedef __attribute__((ext_vector_type(8))) short  short8;
typedef __attribute__((ext_vector_type(4))) float  f32x4;

__device__ __forceinline__ float lo16(unsigned int u) {
    union { unsigned int x; float f; } c; c.x = u << 16; return c.f;
}
__device__ __forceinline__ float hi16(unsigned int u) {
    union { unsigned int x; float f; } c; c.x = u & 0xFFFF0000u; return c.f;
}

// f32 -> bf16 (RNE), returned as raw ushort
__device__ __forceinline__ unsigned short f2bu(float f) {
    union { float f; unsigned int u; } x;
    x.f = f;
    unsigned int r = x.u + 0x7FFFu + ((x.u >> 16) & 1u);
    return (unsigned short)(r >> 16);
}

// ---------------------------------------------------------------------------
// K1: McatT[r*128+e][d] = sum_k w_uir[r][d][k] * w_aor[r][e][k]   (bf16 out)
//     cvec[r*128+e]     = sum_k r_vec[r][k]   * w_aor[r][e][k]    (f32 out)
// ---------------------------------------------------------------------------
__global__ __launch_bounds__(256) void k_precompute(
    const float* __restrict__ w_uir,
    const float* __restrict__ w_aor,
    const float* __restrict__ r_vec,
    unsigned short* __restrict__ McatT,   // [384][128] bf16 bits
    float* __restrict__ cvec)             // [384]
{
    int idx = blockIdx.x * 256 + threadIdx.x;
    if (idx < NREL * 128 * 128) {
        int d = idx & 127;
        int e = (idx >> 7) & 127;
        int r = idx >> 14;
        const float4* pu = reinterpret_cast<const float4*>(w_uir + (r * 128 + d) * 64);
        const float4* pa = reinterpret_cast<const float4*>(w_aor + (r * 128 + e) * 64);
        float acc = 0.f;
        #pragma unroll
        for (int k = 0; k < 16; ++k) {
            float4 a = pu[k], b = pa[k];
            acc += a.x * b.x + a.y * b.y + a.z * b.z + a.w * b.w;
        }
        McatT[(r * 128 + e) * 128 + d] = f2bu(acc);
    } else if (idx < NREL * 128 * 128 + NREL * 128) {
        int j = idx - NREL * 128 * 128;
        int r = j >> 7, e = j & 127;
        const float4* pr = reinterpret_cast<const float4*>(r_vec + r * 64);
        const float4* pa = reinterpret_cast<const float4*>(w_aor + (r * 128 + e) * 64);
        float acc = 0.f;
        #pragma unroll
        for (int k = 0; k < 16; ++k) {
            float4 a = pr[k], b = pa[k];
            acc += a.x * b.x + a.y * b.y + a.z * b.z + a.w * b.w;
        }
        cvec[j] = acc;
    }
}

// ---------------------------------------------------------------------------
// K2 (fused): per block of 16 b's --
//   phase A: stage ui rows (16x128 bf16) to LDS; MFMA M=16,N=384,K=128 with
//            B = McatT from global (L2-resident); vp tile -> LDS (12 KB).
//            vp never touches global memory.
//   phase B: 4 slices x 4 b's: one-shot global_load_lds staging of a/o
//            (40 KB, R8-proven shape) -> consume 80 triples -> out.
// ---------------------------------------------------------------------------
#define K3_BLOCKS (BB / 16)     // 1024
#define UI_OFF 0                // 4096 B  (16 rows x 128 bf16)
#define VP_OFF 4096             // 12288 B (16 b x 384 bf16)
#define AO_OFF 16384            // 40960 B (a 20480 | o 20480)
#define K3_LDS 57344

__device__ __forceinline__ void stage_ao(
    const float* __restrict__ a_emb, const float* __restrict__ o_emb,
    char* lds, size_t t0s, int wv, int lane)
{
    const char* asrc = (const char*)a_emb + t0s * 256;
    const char* osrc = (const char*)o_emb + t0s * 256;
    #pragma unroll
    for (int i = 0; i < 5; ++i) {
        int seg = i * 4 + wv;
        __builtin_amdgcn_global_load_lds(
            (const unsigned int*)(asrc + seg * 1024 + (size_t)lane * 16),
            (unsigned int*)(lds + AO_OFF + seg * 1024), 16, 0, 0);
    }
    #pragma unroll
    for (int i = 0; i < 5; ++i) {
        int seg = i * 4 + wv;
        __builtin_amdgcn_global_load_lds(
            (const unsigned int*)(osrc + seg * 1024 + (size_t)lane * 16),
            (unsigned int*)(lds + AO_OFF + 20480 + seg * 1024), 16, 0, 0);
    }
}

__device__ __forceinline__ void consume_slice(
    const char* lds, int sl, size_t t0s,
    const int* sv, int g, int sub, float* __restrict__ out)
{
    #pragma unroll
    for (int p = 0; p < 5; ++p) {
        const int ltrip = p * 16 + g;
        const int bl    = ltrip / NN;                  // b within slice (0..3)
        const int brow  = sl * 4 + bl;                 // b within block (0..15)
        const int svv   = sv[p];
        float4 af = *(const float4*)(lds + AO_OFF + ltrip * 256 + sub * 16);
        float4 of = *(const float4*)(lds + AO_OFF + 20480 + ltrip * 256 + sub * 16);
        uint2  wa = *(const uint2*)(lds + VP_OFF + brow * 768 + svv * 256 + sub * 8);
        uint2  wo = *(const uint2*)(lds + VP_OFF + brow * 768 + svv * 256 + 128 + sub * 8);
        float r = af.x * lo16(wa.x) + af.y * hi16(wa.x)
                + af.z * lo16(wa.y) + af.w * hi16(wa.y)
                + of.x * lo16(wo.x) + of.y * hi16(wo.x)
                + of.z * lo16(wo.y) + of.w * hi16(wo.y);
        r += __shfl_xor(r, 1, 64);
        r += __shfl_xor(r, 2, 64);
        r += __shfl_xor(r, 4, 64);
        r += __shfl_xor(r, 8, 64);
        if (sub == 0) out[t0s + ltrip] = r;
    }
}

__global__ __launch_bounds__(256) void k_fused(
    const float* __restrict__ u_emb,
    const float* __restrict__ i_emb,
    const float* __restrict__ a_emb,
    const float* __restrict__ o_emb,
    const int* __restrict__ s,
    const unsigned short* __restrict__ McatT,  // [384][128] bf16 bits
    const float* __restrict__ cvec,            // [384]
    float* __restrict__ out)
{
    __shared__ __align__(16) char lds[K3_LDS];

    const int tid  = threadIdx.x;
    const int bid  = blockIdx.x;
    const int wv   = tid >> 6;
    const int lane = tid & 63;
    const int g    = tid >> 4;        // 16-lane group (0..15)
    const int sub  = tid & 15;
    const int lr   = lane & 15;
    const int lk   = (lane >> 4) * 8;

    const int    b0     = bid * 16;            // first b of this block
    const size_t t0blk  = (size_t)bid * 320;   // first triple of this block

    // ---- slice-0 prefetch: DMA a/o + per-lane s (fly during phase A)
    stage_ao(a_emb, o_emb, lds, t0blk, wv, lane);
    int sv0[5];
    #pragma unroll
    for (int p = 0; p < 5; ++p) sv0[p] = s[t0blk + p * 16 + g];

    // ---- phase A1: stage ui rows (16 x 128 f32 -> bf16 LDS)
    {
        const int r  = tid >> 4;          // row 0..15
        const int c8 = (tid & 15) * 8;    // col 0..127 step 8
        const float* src = (c8 < 64)
            ? (u_emb + (size_t)(b0 + r) * 64 + c8)
            : (i_emb + (size_t)(b0 + r) * 64 + (c8 - 64));
        float4 v0 = *(const float4*)(src);
        float4 v1 = *(const float4*)(src + 4);
        unsigned short h[8];
        h[0] = f2bu(v0.x); h[1] = f2bu(v0.y); h[2] = f2bu(v0.z); h[3] = f2bu(v0.w);
        h[4] = f2bu(v1.x); h[5] = f2bu(v1.y); h[6] = f2bu(v1.z); h[7] = f2bu(v1.w);
        *(ushort4*)(lds + UI_OFF + (r * 128 + c8) * 2)       = *(ushort4*)&h[0];
        *(ushort4*)(lds + UI_OFF + (r * 128 + c8) * 2 + 8)   = *(ushort4*)&h[4];
    }
    __syncthreads();   // ui visible; slice-0 DMA also landed

    // ---- phase A2: MFMA -> vp_lds.  wave wv covers cols [wv*96, wv*96+96)
    const unsigned short* ui16 = (const unsigned short*)(lds + UI_OFF);
    #pragma unroll
    for (int nt = 0; nt < 6; ++nt) {
        const int col = wv * 96 + nt * 16 + lr;
        f32x4 acc = {0.f, 0.f, 0.f, 0.f};
        #pragma unroll
        for (int kk = 0; kk < 4; ++kk) {
            short8 afrag = *(const short8*)&ui16[lr * 128 + kk * 32 + lk];
            short8 bfrag = *(const short8*)(McatT + col * 128 + kk * 32 + lk);
            acc = __builtin_amdgcn_mfma_f32_16x16x32_bf16(afrag, bfrag, acc, 0, 0, 0);
        }
        const float cb = cvec[col];
        #pragma unroll
        for (int reg = 0; reg < 4; ++reg) {
            const int brow = (lane >> 4) * 4 + reg;    // b_local 0..15
            *(unsigned short*)(lds + VP_OFF + brow * 768 + col * 2)
                = f2bu(acc[reg] + cb);
        }
    }
    __syncthreads();   // vp_lds complete

    // ---- phase B: slice 0 (already staged), then slices 1..3
    consume_slice(lds, 0, t0blk, sv0, g, sub, out);

    #pragma unroll
    for (int sl = 1; sl < 4; ++sl) {
        __syncthreads();                         // all waves done with prev slice
        const size_t t0s = t0blk + (size_t)sl * 80;
        stage_ao(a_emb, o_emb, lds, t0s, wv, lane);
        int sv[5];
        #pragma unroll
        for (int p = 0; p < 5; ++p) sv[p] = s[t0s + p * 16 + g];
        __syncthreads();                         // slice landed (full drain)
        consume_slice(lds, sl, t0s, sv, g, sub, out);
    }
}

// ---------------------------------------------------------------------------
extern "C" void kernel_launch(void* const* d_in, const int* in_sizes, int n_in,
                              void* d_out, int out_size, void* d_ws, size_t ws_size,
                              hipStream_t stream) {
    const float* u_emb = (const float*)d_in[0];
    const float* i_emb = (const float*)d_in[1];
    const float* a_emb = (const float*)d_in[2];
    const float* o_emb = (const float*)d_in[3];
    const int*   s     = (const int*)d_in[4];
    const float* w_uir = (const float*)d_in[5];
    const float* w_aor = (const float*)d_in[6];
    const float* r_vec = (const float*)d_in[7];
    float* out = (float*)d_out;

    char* ws = (char*)d_ws;
    unsigned short* McatT = (unsigned short*)ws;              // 98304 B
    float*          cvec  = (float*)(ws + 98304);             // 1536 B

    k_precompute<<<194, 256, 0, stream>>>(w_uir, w_aor, r_vec, McatT, cvec);
    k_fused<<<K3_BLOCKS, 256, 0, stream>>>(u_emb, i_emb, a_emb, o_emb, s,
                                           McatT, cvec, out);
}

// Round 13
// 45.423 us; speedup vs baseline: 1.2042x; 1.0216x over previous
//
#include <hip/hip_runtime.h>
#include <hip/hip_bf16.h>

// Problem constants: B=16384, N=20, D=64, R=3, K=64
#define BB   16384
#define NN   20
#define NREL 3

typedef __attribute__((ext_vector_type(8))) short  short8;
typedef __attribute__((ext_vector_type(4))) float  f32x4;

__device__ __forceinline__ float lo16(unsigned int u) {
    union { unsigned int x; float f; } c; c.x = u << 16; return c.f;
}
__device__ __forceinline__ float hi16(unsigned int u) {
    union { unsigned int x; float f; } c; c.x = u & 0xFFFF0000u; return c.f;
}

// f32 -> bf16 (RNE), returned as raw ushort
__device__ __forceinline__ unsigned short f2bu(float f) {
    union { float f; unsigned int u; } x;
    x.f = f;
    unsigned int r = x.u + 0x7FFFu + ((x.u >> 16) & 1u);
    return (unsigned short)(r >> 16);
}

// ---------------------------------------------------------------------------
// K1: McatT[r*128+e][d] = sum_k w_uir[r][d][k] * w_aor[r][e][k]   (bf16 out)
//     cvec[r*128+e]     = sum_k r_vec[r][k]   * w_aor[r][e][k]    (f32 out)
// ---------------------------------------------------------------------------
__global__ __launch_bounds__(256) void k_precompute(
    const float* __restrict__ w_uir,
    const float* __restrict__ w_aor,
    const float* __restrict__ r_vec,
    unsigned short* __restrict__ McatT,   // [384][128] bf16 bits
    float* __restrict__ cvec)             // [384]
{
    int idx = blockIdx.x * 256 + threadIdx.x;
    if (idx < NREL * 128 * 128) {
        int d = idx & 127;
        int e = (idx >> 7) & 127;
        int r = idx >> 14;
        const float4* pu = reinterpret_cast<const float4*>(w_uir + (r * 128 + d) * 64);
        const float4* pa = reinterpret_cast<const float4*>(w_aor + (r * 128 + e) * 64);
        float acc = 0.f;
        #pragma unroll
        for (int k = 0; k < 16; ++k) {
            float4 a = pu[k], b = pa[k];
            acc += a.x * b.x + a.y * b.y + a.z * b.z + a.w * b.w;
        }
        McatT[(r * 128 + e) * 128 + d] = f2bu(acc);
    } else if (idx < NREL * 128 * 128 + NREL * 128) {
        int j = idx - NREL * 128 * 128;
        int r = j >> 7, e = j & 127;
        const float4* pr = reinterpret_cast<const float4*>(r_vec + r * 64);
        const float4* pa = reinterpret_cast<const float4*>(w_aor + (r * 128 + e) * 64);
        float acc = 0.f;
        #pragma unroll
        for (int k = 0; k < 16; ++k) {
            float4 a = pr[k], b = pa[k];
            acc += a.x * b.x + a.y * b.y + a.z * b.z + a.w * b.w;
        }
        cvec[j] = acc;
    }
}

// ---------------------------------------------------------------------------
// K2 (fused, 512-thread blocks): per block of 16 b's --
//   phase A: ui rows (16x128) -> LDS bf16; MFMA M=16,N=384,K=128 with
//            B = McatT from global (L2-resident); vp tile (12KB) -> LDS.
//   phase B: 8 double-buffered slices of 2 b's (20KB each):
//            stage(sl+1) -> consume(sl) -> sync. The next slice's DMA is
//            in flight DURING consume; 2 blocks/CU x 8 waves = 16 waves/CU.
// ---------------------------------------------------------------------------
#define K3_BLOCKS (BB / 16)     // 1024
#define UI_OFF 0                // 4096 B  (16 rows x 128 bf16)
#define VP_OFF 4096             // 12288 B (16 b x 384 bf16)
#define SL_OFF 16384            // 2 x 20480 B slice buffers (a 10240 | o 10240)
#define SL_SZ  20480
#define K3_LDS 57344

__device__ __forceinline__ void dma_seg(
    char* buf, const char* asrc, const char* osrc, int seg, int lane)
{
    const char* src = (seg < 10) ? (asrc + seg * 1024 + (size_t)lane * 16)
                                 : (osrc + (seg - 10) * 1024 + (size_t)lane * 16);
    __builtin_amdgcn_global_load_lds((const unsigned int*)src,
                                     (unsigned int*)(buf + seg * 1024), 16, 0, 0);
}

// stage one 2-b slice (20 segs of 1KB) across 8 waves: wv, wv+8, [wv+16 if wv<4]
__device__ __forceinline__ void stage_slice(
    const float* __restrict__ a_emb, const float* __restrict__ o_emb,
    char* buf, size_t t0s, int wv, int lane)
{
    const char* asrc = (const char*)a_emb + t0s * 256;
    const char* osrc = (const char*)o_emb + t0s * 256;
    dma_seg(buf, asrc, osrc, wv, lane);
    dma_seg(buf, asrc, osrc, wv + 8, lane);
    if (wv < 4) dma_seg(buf, asrc, osrc, wv + 16, lane);
}

// consume one 2-b slice: 40 triples, 32 groups of 16 lanes
__device__ __forceinline__ void consume_slice(
    const char* lds, const char* buf, int sl, size_t t0s,
    int sv0, int sv1, int g, int sub, float* __restrict__ out)
{
    // pass 0: triples 0..31
    {
        const int ltrip = g;
        const int brow  = sl * 2 + (ltrip / NN);
        float4 af = *(const float4*)(buf + ltrip * 256 + sub * 16);
        float4 of = *(const float4*)(buf + 10240 + ltrip * 256 + sub * 16);
        uint2  wa = *(const uint2*)(lds + VP_OFF + brow * 768 + sv0 * 256 + sub * 8);
        uint2  wo = *(const uint2*)(lds + VP_OFF + brow * 768 + sv0 * 256 + 128 + sub * 8);
        float r = af.x * lo16(wa.x) + af.y * hi16(wa.x)
                + af.z * lo16(wa.y) + af.w * hi16(wa.y)
                + of.x * lo16(wo.x) + of.y * hi16(wo.x)
                + of.z * lo16(wo.y) + of.w * hi16(wo.y);
        r += __shfl_xor(r, 1, 64);
        r += __shfl_xor(r, 2, 64);
        r += __shfl_xor(r, 4, 64);
        r += __shfl_xor(r, 8, 64);
        if (sub == 0) out[t0s + ltrip] = r;
    }
    // pass 1: triples 32..39 (groups 0..7)
    if (g < 8) {
        const int ltrip = 32 + g;
        const int brow  = sl * 2 + 1;               // 32..39 are all b-local 1
        float4 af = *(const float4*)(buf + ltrip * 256 + sub * 16);
        float4 of = *(const float4*)(buf + 10240 + ltrip * 256 + sub * 16);
        uint2  wa = *(const uint2*)(lds + VP_OFF + brow * 768 + sv1 * 256 + sub * 8);
        uint2  wo = *(const uint2*)(lds + VP_OFF + brow * 768 + sv1 * 256 + 128 + sub * 8);
        float r = af.x * lo16(wa.x) + af.y * hi16(wa.x)
                + af.z * lo16(wa.y) + af.w * hi16(wa.y)
                + of.x * lo16(wo.x) + of.y * hi16(wo.x)
                + of.z * lo16(wo.y) + of.w * hi16(wo.y);
        r += __shfl_xor(r, 1, 64);
        r += __shfl_xor(r, 2, 64);
        r += __shfl_xor(r, 4, 64);
        r += __shfl_xor(r, 8, 64);
        if (sub == 0) out[t0s + ltrip] = r;
    }
}

__global__ __launch_bounds__(512) void k_fused(
    const float* __restrict__ u_emb,
    const float* __restrict__ i_emb,
    const float* __restrict__ a_emb,
    const float* __restrict__ o_emb,
    const int* __restrict__ s,
    const unsigned short* __restrict__ McatT,  // [384][128] bf16 bits
    const float* __restrict__ cvec,            // [384]
    float* __restrict__ out)
{
    __shared__ __align__(16) char lds[K3_LDS];

    const int tid  = threadIdx.x;
    const int bid  = blockIdx.x;
    const int wv   = tid >> 6;        // 0..7
    const int lane = tid & 63;
    const int g    = tid >> 4;        // 16-lane group (0..31)
    const int sub  = tid & 15;
    const int lr   = lane & 15;
    const int lk   = (lane >> 4) * 8;

    const int    b0    = bid * 16;            // first b of this block
    const size_t t0blk = (size_t)bid * 320;   // first triple of this block

    // ---- slice-0 prefetch (flies during phase A) + its s values
    stage_slice(a_emb, o_emb, lds + SL_OFF, t0blk, wv, lane);
    int svc0 = s[t0blk + g];
    int svc1 = (g < 8) ? s[t0blk + 32 + g] : 0;

    // ---- phase A1: stage ui rows (16 x 128 f32 -> bf16 LDS), 4 floats/thread
    {
        const int r  = tid >> 5;          // row 0..15
        const int c4 = (tid & 31) * 4;    // col 0..124 step 4
        const float* src = (c4 < 64)
            ? (u_emb + (size_t)(b0 + r) * 64 + c4)
            : (i_emb + (size_t)(b0 + r) * 64 + (c4 - 64));
        float4 v = *(const float4*)(src);
        unsigned short h[4];
        h[0] = f2bu(v.x); h[1] = f2bu(v.y); h[2] = f2bu(v.z); h[3] = f2bu(v.w);
        *(ushort4*)(lds + UI_OFF + (r * 128 + c4) * 2) = *(ushort4*)&h[0];
    }
    __syncthreads();   // ui visible; slice-0 DMA also landed

    // ---- phase A2: MFMA -> vp_lds.  wave wv covers cols [wv*48, wv*48+48)
    const unsigned short* ui16 = (const unsigned short*)(lds + UI_OFF);
    #pragma unroll
    for (int nt = 0; nt < 3; ++nt) {
        const int col = wv * 48 + nt * 16 + lr;
        f32x4 acc = {0.f, 0.f, 0.f, 0.f};
        #pragma unroll
        for (int kk = 0; kk < 4; ++kk) {
            short8 afrag = *(const short8*)&ui16[lr * 128 + kk * 32 + lk];
            short8 bfrag = *(const short8*)(McatT + col * 128 + kk * 32 + lk);
            acc = __builtin_amdgcn_mfma_f32_16x16x32_bf16(afrag, bfrag, acc, 0, 0, 0);
        }
        const float cb = cvec[col];
        #pragma unroll
        for (int reg = 0; reg < 4; ++reg) {
            const int brow = (lane >> 4) * 4 + reg;    // b_local 0..15
            *(unsigned short*)(lds + VP_OFF + brow * 768 + col * 2)
                = f2bu(acc[reg] + cb);
        }
    }
    __syncthreads();   // vp_lds complete

    // ---- phase B: 8 slices, double-buffered, stage-ahead
    #pragma unroll
    for (int sl = 0; sl < 8; ++sl) {
        int svn0 = 0, svn1 = 0;
        if (sl < 7) {
            const size_t t0n = t0blk + (size_t)(sl + 1) * 40;
            stage_slice(a_emb, o_emb, lds + SL_OFF + ((sl + 1) & 1) * SL_SZ,
                        t0n, wv, lane);               // flies during consume
            svn0 = s[t0n + g];
            svn1 = (g < 8) ? s[t0n + 32 + g] : 0;
        }
        consume_slice(lds, lds + SL_OFF + (sl & 1) * SL_SZ, sl,
                      t0blk + (size_t)sl * 40, svc0, svc1, g, sub, out);
        __syncthreads();   // drains: slice sl+1 landed; all waves off buf(sl)
        svc0 = svn0; svc1 = svn1;
    }
}

// ---------------------------------------------------------------------------
extern "C" void kernel_launch(void* const* d_in, const int* in_sizes, int n_in,
                              void* d_out, int out_size, void* d_ws, size_t ws_size,
                              hipStream_t stream) {
    const float* u_emb = (const float*)d_in[0];
    const float* i_emb = (const float*)d_in[1];
    const float* a_emb = (const float*)d_in[2];
    const float* o_emb = (const float*)d_in[3];
    const int*   s     = (const int*)d_in[4];
    const float* w_uir = (const float*)d_in[5];
    const float* w_aor = (const float*)d_in[6];
    const float* r_vec = (const float*)d_in[7];
    float* out = (float*)d_out;

    char* ws = (char*)d_ws;
    unsigned short* McatT = (unsigned short*)ws;              // 98304 B
    float*          cvec  = (float*)(ws + 98304);             // 1536 B

    k_precompute<<<194, 256, 0, stream>>>(w_uir, w_aor, r_vec, McatT, cvec);
    k_fused<<<K3_BLOCKS, 512, 0, stream>>>(u_emb, i_emb, a_emb, o_emb, s,
                                           McatT, cvec, out);
}